// Round 11
// baseline (161.467 us; speedup 1.0000x reference)
//
#include <hip/hip_runtime.h>
#include <math.h>

// Problem constants
#define NB 4
#define TT 256
#define DMODEL 1024
#define NE 16
#define DLQ 64
#define NH 4
#define HD 16
#define SEQL 17
#define NTOK 1024   // NB*TT

// Workspace layout (float offsets). ws is ~268 MB; regions are private.
static constexpr size_t WS_EF    = 0;          // 1024x1024 fp32 ef partial P0
static constexpr size_t WS_AH    = 1048576;    // x hi bf16 plane, frag-swizzled
static constexpr size_t WS_AL    = 1572864;    // x lo
static constexpr size_t WS_BH    = 2097152;    // w_down hi
static constexpr size_t WS_BL    = 2621440;    // w_down lo
static constexpr size_t WS_P1    = 3145728;    // K-split partial P1
static constexpr size_t WS_ACT   = 4194304;    // act bf16 [2048][64]
static constexpr size_t WS_AIWFH = 4259840;    // attn_in_w hi frags (12288 sh)
static constexpr size_t WS_AIWFL = 4265984;    // attn_in_w lo frags
static constexpr size_t WS_AOWFH = 4272128;    // attn_out_w hi frags (4096 sh)
static constexpr size_t WS_AOWFL = 4274176;    // attn_out_w lo frags
static constexpr size_t WS_G1FH  = 4276224;    // g1_w hi frags (8192 sh)
static constexpr size_t WS_G1FL  = 4280320;    // g1_w lo frags
static constexpr size_t WS_PR    = 4308992;    // 1024x16 probs
static constexpr size_t WS_TI    = 4325376;    // 1024 packed ints: t0 | t1<<8
static constexpr size_t WS_GCTX  = 4326400;    // 4x64
static constexpr size_t WS_XPART = 4465664;    // [4][8][1024] fp32 x col-sum partials
static constexpr size_t WS_UPF   = 4498432;    // w_up bf16 frag planes (256 tiles x 4096 sh)

typedef __attribute__((ext_vector_type(8))) short short8;
typedef __attribute__((ext_vector_type(4))) short short4v;
typedef __attribute__((ext_vector_type(4))) float f32x4;

__device__ __forceinline__ float gelu_exact(float x) {
    return 0.5f * x * (1.0f + erff(x * 0.70710678118654752f));
}

__device__ __forceinline__ unsigned short f2bf(float f) {
    unsigned int u = __float_as_uint(f);
    unsigned int r = (u + 0x7fffu + ((u >> 16) & 1u)) >> 16;
    return (unsigned short)r;
}
__device__ __forceinline__ float bf2f(unsigned short h) {
    return __uint_as_float(((unsigned int)h) << 16);
}

// DPP row_ror all-reduce within 16-lane rows: VALU pipe, zero LDS ops.
#define DPP_ADD(v, ctrl) { int _m = __builtin_amdgcn_update_dpp(0, __float_as_int(v), ctrl, 0xF, 0xF, true); \
                           v += __int_as_float(_m); }
__device__ __forceinline__ float rsum16(float v) {
    DPP_ADD(v, 0x128);  // row_ror:8
    DPP_ADD(v, 0x124);  // row_ror:4
    DPP_ADD(v, 0x122);  // row_ror:2
    DPP_ADD(v, 0x121);  // row_ror:1
    return v;
}
__device__ __forceinline__ float rsum64(float v) {
    v = rsum16(v);
    v += __shfl_xor(v, 16);
    v += __shfl_xor(v, 32);
    return v;
}

// K0 (fused). r10 post-mortem: boundary ≈ 4-5us each; r10's memset fold
// confirmed at −4.3us. This round: blocks 801..1056 pre-convert w_up into
// bf16 frag planes (hi only — moe already used single bf16, bit-identical)
// so k_moe_gemm's B-operand becomes two coalesced 16B loads instead of a
// 16-load 4KB-strided gather + 32 f2bf on its critical path.
// Blocks 0..511: x / w_down hi/lo planes. Block 512: weight frag planes.
// Blocks 513..544: x col-sum partials. Blocks 545..800: zero out.
__global__ __launch_bounds__(256) void k_prep(const float* __restrict__ x,
                                              const float* __restrict__ wdn,
                                              const float* __restrict__ aiw,
                                              const float* __restrict__ aow,
                                              const float* __restrict__ g1w,
                                              const float* __restrict__ w_up,
                                              float* __restrict__ ws,
                                              float* __restrict__ out) {
    __shared__ __attribute__((aligned(16))) unsigned short sh_h[4096];
    __shared__ __attribute__((aligned(16))) unsigned short sh_l[4096];
    int bi = blockIdx.x;
    int tid = threadIdx.x;
    if (bi < 512) {
        int which = bi >> 8;            // 0: x, 1: w_down
        int tix = bi & 255;             // tile index = nb*16 + kb
        int nb = tix >> 4, kb = tix & 15;
        const float* src = (which ? wdn : x) + (size_t)(nb * 64) * DMODEL + kb * 64;
        int r = tid >> 2;               // 0..63 (tile row)
        int c4 = (tid & 3) * 4;         // col sub-chunk
#pragma unroll
        for (int q = 0; q < 4; ++q) {
            int cc = q * 16 + c4;       // tile col of first elem
            float4 v = *(const float4*)(src + (size_t)r * DMODEL + cc);
            float a[4] = {v.x, v.y, v.z, v.w};
            unsigned short h4[4], l4[4];
#pragma unroll
            for (int k = 0; k < 4; ++k) {
                h4[k] = f2bf(a[k]);
                l4[k] = f2bf(a[k] - bf2f(h4[k]));
            }
            int st = r >> 4;
            int ks = cc >> 5;
            int ln = (r & 15) + (((cc >> 3) & 3) << 4);
            int jb = cc & 7;            // 0 or 4
            size_t off = (size_t)st * 1024 + ks * 512 + ln * 8 + jb;
            *(short4v*)(sh_h + off) = *(short4v*)h4;
            *(short4v*)(sh_l + off) = *(short4v*)l4;
        }
        __syncthreads();
        unsigned short* hp = (unsigned short*)(ws + (which ? WS_BH : WS_AH)) + (size_t)tix * 4096;
        unsigned short* lp = (unsigned short*)(ws + (which ? WS_BL : WS_AL)) + (size_t)tix * 4096;
        *(short8*)(hp + tid * 16)     = *(short8*)(sh_h + tid * 16);
        *(short8*)(hp + tid * 16 + 8) = *(short8*)(sh_h + tid * 16 + 8);
        *(short8*)(lp + tid * 16)     = *(short8*)(sh_l + tid * 16);
        *(short8*)(lp + tid * 16 + 8) = *(short8*)(sh_l + tid * 16 + 8);
    } else if (bi == 512) {
        unsigned short* fh = (unsigned short*)(ws + WS_AIWFH);
        unsigned short* fl = (unsigned short*)(ws + WS_AIWFL);
        for (int idx = tid; idx < 12 * 2 * 64; idx += 256) {
            int nt = idx >> 7, kf = (idx >> 6) & 1, l = idx & 63;
            int row = nt * 16 + (l & 15);
            int k = kf * 32 + ((l >> 4) << 3);
            const float* src = aiw + (size_t)row * DLQ + k;
            unsigned short h8[8], l8[8];
#pragma unroll
            for (int j = 0; j < 8; ++j) {
                h8[j] = f2bf(src[j]);
                l8[j] = f2bf(src[j] - bf2f(h8[j]));
            }
            size_t off = (size_t)(nt * 2 + kf) * 512 + l * 8;
            *(short8*)(fh + off) = *(short8*)h8;
            *(short8*)(fl + off) = *(short8*)l8;
        }
        unsigned short* gh = (unsigned short*)(ws + WS_AOWFH);
        unsigned short* gl = (unsigned short*)(ws + WS_AOWFL);
        for (int idx = tid; idx < 4 * 2 * 64; idx += 256) {
            int nt = idx >> 7, kf = (idx >> 6) & 1, l = idx & 63;
            int row = nt * 16 + (l & 15);
            int k = kf * 32 + ((l >> 4) << 3);
            const float* src = aow + (size_t)row * DLQ + k;
            unsigned short h8[8], l8[8];
#pragma unroll
            for (int j = 0; j < 8; ++j) {
                h8[j] = f2bf(src[j]);
                l8[j] = f2bf(src[j] - bf2f(h8[j]));
            }
            size_t off = (size_t)(nt * 2 + kf) * 512 + l * 8;
            *(short8*)(gh + off) = *(short8*)h8;
            *(short8*)(gl + off) = *(short8*)l8;
        }
        // g1_w [128][64] -> 8 N-tiles of hi/lo frags (rides attn phase 2)
        unsigned short* qh = (unsigned short*)(ws + WS_G1FH);
        unsigned short* ql = (unsigned short*)(ws + WS_G1FL);
        for (int idx = tid; idx < 8 * 2 * 64; idx += 256) {
            int nt = idx >> 7, kf = (idx >> 6) & 1, l = idx & 63;
            int row = nt * 16 + (l & 15);
            int k = kf * 32 + ((l >> 4) << 3);
            const float* src = g1w + (size_t)row * DLQ + k;
            unsigned short h8[8], l8[8];
#pragma unroll
            for (int j = 0; j < 8; ++j) {
                h8[j] = f2bf(src[j]);
                l8[j] = f2bf(src[j] - bf2f(h8[j]));
            }
            size_t off = (size_t)(nt * 2 + kf) * 512 + l * 8;
            *(short8*)(qh + off) = *(short8*)h8;
            *(short8*)(ql + off) = *(short8*)l8;
        }
    } else if (bi < 545) {
        // x column-sum partials: idx = b*8 + j, rows b*256+j*32 .. +31
        int idx = bi - 513;           // 0..31
        int b = idx >> 3, j = idx & 7;
        const float* xb = x + (size_t)(b * 256 + j * 32) * DMODEL + tid * 4;
        float4 acc = {0.f, 0.f, 0.f, 0.f};
#pragma unroll 8
        for (int r = 0; r < 32; ++r) {
            float4 v = *(const float4*)(xb + (size_t)r * DMODEL);
            acc.x += v.x; acc.y += v.y; acc.z += v.z; acc.w += v.w;
        }
        *(float4*)(ws + WS_XPART + (size_t)idx * DMODEL + tid * 4) = acc;
    } else if (bi < 801) {
        // zero out[0 .. NTOK*DMODEL): 256 blocks x 4096 floats exactly.
        int z = bi - 545;             // 0..255
        float4 zz = {0.f, 0.f, 0.f, 0.f};
        float* op = out + (size_t)z * 4096;
#pragma unroll
        for (int q = 0; q < 4; ++q)
            *(float4*)(op + q * 1024 + tid * 4) = zz;
    } else {
        // w_up bf16 frag tiles: idx = e*16+ct. Tile = w_up[e][k 0..63]
        // [ct*64 + m 0..63]. Frag map (verified == moe's consumer):
        // off = st*1024 + ks*512 + ln*8 + j, st=m>>4, ks=k>>5,
        // ln=((k>>3)&3)*16 + (m&15), j=k&7. Coalesced src read (256B/row
        // across 4 threads), per-element LDS scatter, contiguous write.
        int idx = bi - 801;           // 0..255
        int e = idx >> 4, ct = idx & 15;
        const float* src = w_up + (size_t)e * DLQ * DMODEL + ct * 64;
        int k = tid >> 2;             // 0..63
        int m4 = (tid & 3) * 4;
        int ks = k >> 5, j = k & 7, lnh = ((k >> 3) & 3) << 4;
#pragma unroll
        for (int q = 0; q < 4; ++q) {
            int m = q * 16 + m4;
            float4 v = *(const float4*)(src + (size_t)k * DMODEL + m);
            float a[4] = {v.x, v.y, v.z, v.w};
#pragma unroll
            for (int i = 0; i < 4; ++i) {
                int ln = lnh + ((m + i) & 15);
                sh_h[(size_t)q * 1024 + ks * 512 + ln * 8 + j] = f2bf(a[i]);
            }
        }
        __syncthreads();
        unsigned short* up = (unsigned short*)(ws + WS_UPF) + (size_t)idx * 4096;
        *(short8*)(up + tid * 16)     = *(short8*)(sh_h + tid * 16);
        *(short8*)(up + tid * 16 + 8) = *(short8*)(sh_h + tid * 16 + 8);
    }
}

// K2: ef GEMM (blocks 0..511, XCD-rectangle swizzle, global_load_lds from
// pre-converted planes) + FOUR gctx tail blocks (bi=512..515, one batch
// each, hidden under the GEMM wall). g1/g2 live in k_attn2 (g1 via MFMA).
__global__ __launch_bounds__(256) void k_ef_mfma(const float* __restrict__ gp_w,
                                                 const float* __restrict__ gp_b,
                                                 float* __restrict__ ws) {
    __shared__ __attribute__((aligned(16))) unsigned short smem[16384];
    int tid = threadIdx.x;
    int bi = blockIdx.x;

    if (bi >= 512) {
        // ---- gctx tail: batch q; wave wv owns cols c = wv*16..+15 ----
        int q = bi - 512;
        int wv = tid >> 6, l = tid & 63;
        float4 xa[4] = {{0.f,0.f,0.f,0.f},{0.f,0.f,0.f,0.f},
                        {0.f,0.f,0.f,0.f},{0.f,0.f,0.f,0.f}};
        const float* xp = ws + WS_XPART + (size_t)q * 8 * DMODEL + l * 16;
#pragma unroll
        for (int j = 0; j < 8; ++j) {
#pragma unroll
            for (int qq = 0; qq < 4; ++qq) {
                float4 v = *(const float4*)(xp + (size_t)j * DMODEL + qq * 4);
                xa[qq].x += v.x; xa[qq].y += v.y; xa[qq].z += v.z; xa[qq].w += v.w;
            }
        }
        float xm[16];
#pragma unroll
        for (int qq = 0; qq < 4; ++qq) {
            xm[qq * 4 + 0] = xa[qq].x * (1.0f / TT);
            xm[qq * 4 + 1] = xa[qq].y * (1.0f / TT);
            xm[qq * 4 + 2] = xa[qq].z * (1.0f / TT);
            xm[qq * 4 + 3] = xa[qq].w * (1.0f / TT);
        }
#pragma unroll 4
        for (int cq = 0; cq < 16; ++cq) {
            int c = wv * 16 + cq;
            const float* gw = gp_w + (size_t)c * DMODEL + l * 16;
            float s = 0.f;
#pragma unroll
            for (int qq = 0; qq < 4; ++qq) {
                float4 w4 = *(const float4*)(gw + qq * 4);
                s += xm[qq * 4 + 0] * w4.x + xm[qq * 4 + 1] * w4.y +
                     xm[qq * 4 + 2] * w4.z + xm[qq * 4 + 3] * w4.w;
            }
            s = rsum64(s);
            if (l == 0) ws[WS_GCTX + q * DLQ + c] = s + gp_b[c];
        }
        return;
    }

    // ---- ef GEMM ----
    int xcd = bi & 7;
    int g   = bi >> 3;
    int kz  = g >> 5;
    int rem = g & 31;
    int nb  = (xcd >> 1) * 4 + (rem >> 3);
    int mb  = (xcd & 1) * 8 + (rem & 7);

    const unsigned short* AhP = (const unsigned short*)(ws + WS_AH);
    const unsigned short* AlP = (const unsigned short*)(ws + WS_AL);
    const unsigned short* BhP = (const unsigned short*)(ws + WS_BH);
    const unsigned short* BlP = (const unsigned short*)(ws + WS_BL);
    int w = tid >> 6, l = tid & 63;
    int wn = (w >> 1) * 32, wm = (w & 1) * 32;
    int stA = wn >> 4, stB = wm >> 4;
    f32x4 acc00 = {0.f, 0.f, 0.f, 0.f}, acc01 = acc00, acc10 = acc00, acc11 = acc00;

    for (int it = 0; it < 8; ++it) {
        int kb = kz * 8 + it;
        const char* srcs[4] = {
            (const char*)(AhP + (size_t)(nb * 16 + kb) * 4096),
            (const char*)(AlP + (size_t)(nb * 16 + kb) * 4096),
            (const char*)(BhP + (size_t)(mb * 16 + kb) * 4096),
            (const char*)(BlP + (size_t)(mb * 16 + kb) * 4096)};
#pragma unroll
        for (int p = 0; p < 4; ++p) {
#pragma unroll
            for (int h = 0; h < 2; ++h) {
                __builtin_amdgcn_global_load_lds(
                    (const __attribute__((address_space(1))) void*)(srcs[p] + h * 4096 + tid * 16),
                    (__attribute__((address_space(3))) void*)((char*)smem + p * 8192 + h * 4096 + tid * 16),
                    16, 0, 0);
            }
        }
        __syncthreads();
        const unsigned short* Ah = smem;
        const unsigned short* Al = smem + 4096;
        const unsigned short* Bh = smem + 8192;
        const unsigned short* Bl = smem + 12288;
#pragma unroll
        for (int ks = 0; ks < 2; ++ks) {
            short8 ah0 = *(const short8*)(Ah + (stA + 0) * 1024 + ks * 512 + l * 8);
            short8 ah1 = *(const short8*)(Ah + (stA + 1) * 1024 + ks * 512 + l * 8);
            short8 al0 = *(const short8*)(Al + (stA + 0) * 1024 + ks * 512 + l * 8);
            short8 al1 = *(const short8*)(Al + (stA + 1) * 1024 + ks * 512 + l * 8);
            short8 bh0 = *(const short8*)(Bh + (stB + 0) * 1024 + ks * 512 + l * 8);
            short8 bh1 = *(const short8*)(Bh + (stB + 1) * 1024 + ks * 512 + l * 8);
            short8 bl0 = *(const short8*)(Bl + (stB + 0) * 1024 + ks * 512 + l * 8);
            short8 bl1 = *(const short8*)(Bl + (stB + 1) * 1024 + ks * 512 + l * 8);
            acc00 = __builtin_amdgcn_mfma_f32_16x16x32_bf16(ah0, bh0, acc00, 0, 0, 0);
            acc00 = __builtin_amdgcn_mfma_f32_16x16x32_bf16(al0, bh0, acc00, 0, 0, 0);
            acc00 = __builtin_amdgcn_mfma_f32_16x16x32_bf16(ah0, bl0, acc00, 0, 0, 0);
            acc01 = __builtin_amdgcn_mfma_f32_16x16x32_bf16(ah0, bh1, acc01, 0, 0, 0);
            acc01 = __builtin_amdgcn_mfma_f32_16x16x32_bf16(al0, bh1, acc01, 0, 0, 0);
            acc01 = __builtin_amdgcn_mfma_f32_16x16x32_bf16(ah0, bl1, acc01, 0, 0, 0);
            acc10 = __builtin_amdgcn_mfma_f32_16x16x32_bf16(ah1, bh0, acc10, 0, 0, 0);
            acc10 = __builtin_amdgcn_mfma_f32_16x16x32_bf16(al1, bh0, acc10, 0, 0, 0);
            acc10 = __builtin_amdgcn_mfma_f32_16x16x32_bf16(ah1, bl0, acc10, 0, 0, 0);
            acc11 = __builtin_amdgcn_mfma_f32_16x16x32_bf16(ah1, bh1, acc11, 0, 0, 0);
            acc11 = __builtin_amdgcn_mfma_f32_16x16x32_bf16(al1, bh1, acc11, 0, 0, 0);
            acc11 = __builtin_amdgcn_mfma_f32_16x16x32_bf16(ah1, bl1, acc11, 0, 0, 0);
        }
        __syncthreads();
    }
    int cr = (l >> 4) * 4, cc = l & 15;
    int n0 = nb * 64;
    float* P = ws + (kz == 0 ? WS_EF : WS_P1);
    int m0 = mb * 64;
#pragma unroll
    for (int r = 0; r < 4; ++r) {
        P[(size_t)(n0 + wn + cr + r) * DMODEL + (m0 + wm + cc)]           = acc00[r];
        P[(size_t)(n0 + wn + cr + r) * DMODEL + (m0 + wm + 16 + cc)]      = acc01[r];
        P[(size_t)(n0 + wn + 16 + cr + r) * DMODEL + (m0 + wm + cc)]      = acc10[r];
        P[(size_t)(n0 + wn + 16 + cr + r) * DMODEL + (m0 + wm + 16 + cc)] = acc11[r];
    }
}

// K3: one token per block, FOUR waves. MFMA qkv/attn_out + g1-preacts,
// DPP reduces, ACT epilogue. (r6/r8/r10-proven, byte-identical.)
__global__ __launch_bounds__(256) void k_attn2(const float* __restrict__ pos_embed,
                                               const float* __restrict__ attn_in_b,
                                               const float* __restrict__ attn_out_b,
                                               const float* __restrict__ ln_w,
                                               const float* __restrict__ ln_b,
                                               const float* __restrict__ ls_w,
                                               const float* __restrict__ ls_b,
                                               const float* __restrict__ g1_b,
                                               const float* __restrict__ g2_w,
                                               const float* __restrict__ g2_b,
                                               float* __restrict__ ws) {
    int n = blockIdx.x;
    int w = threadIdx.x >> 6;    // 0..3
    int l = threadIdx.x & 63;
    int b = n >> 8;

    __shared__ float qkv[SEQL * 200];
    __shared__ __attribute__((aligned(16))) char ubuf[8192];   // sH/sL then ao
    __shared__ __attribute__((aligned(16))) unsigned short ctxH[1024];
    __shared__ __attribute__((aligned(16))) unsigned short ctxL[1024];
    __shared__ float lgv_sh[NE];
    __shared__ float hsh[128];   // g1 preacts (bias added, gelu at read)
    unsigned short* sH = (unsigned short*)ubuf;
    unsigned short* sL = (unsigned short*)(ubuf + 4096);
    float* ao = (float*)ubuf;

    // Phase 1: seq = (P0+P1)[n] + pos (row 0 = gctx); column l in regs.
    float seqc[SEQL];
    float gcv = ws[WS_GCTX + b * DLQ + l];
    {
        const float* efp0 = ws + WS_EF + (size_t)n * DMODEL;
        const float* efp1 = ws + WS_P1 + (size_t)n * DMODEL;
#pragma unroll
        for (int i = 0; i < SEQL; ++i) {
            float s = (i == 0) ? gcv
                               : efp0[(i - 1) * DLQ + l] + efp1[(i - 1) * DLQ + l] +
                                 pos_embed[(i - 1) * DLQ + l];
            seqc[i] = s;
            int lo_r = w * 5, hi_r = w * 5 + 4;
            if (i >= lo_r && i <= hi_r) {
                unsigned short hs = f2bf(s);
                unsigned short lsv = f2bf(s - bf2f(hs));
                int mt = i >> 4;
                int ls = (i & 15) + (((l >> 3) & 3) << 4);
                int kf = l >> 5;
                int j = l & 7;
                size_t off = (size_t)(mt * 2 + kf) * 512 + ls * 8 + j;
                sH[off] = hs;
                sL[off] = lsv;
            }
        }
    }
    __syncthreads();

    // Phase 2: qkv = seq @ aiw^T (wave w: tiles w*3..+2) AND g1 preacts
    {
        const unsigned short* fh = (const unsigned short*)(ws + WS_AIWFH);
        const unsigned short* fl = (const unsigned short*)(ws + WS_AIWFL);
        const unsigned short* qh = (const unsigned short*)(ws + WS_G1FH);
        const unsigned short* ql = (const unsigned short*)(ws + WS_G1FL);
        f32x4 acc[3][2];
        f32x4 accg[2];
#pragma unroll
        for (int t = 0; t < 3; ++t)
#pragma unroll
            for (int m = 0; m < 2; ++m) acc[t][m] = (f32x4){0.f, 0.f, 0.f, 0.f};
#pragma unroll
        for (int t = 0; t < 2; ++t) accg[t] = (f32x4){0.f, 0.f, 0.f, 0.f};
#pragma unroll
        for (int kf = 0; kf < 2; ++kf) {
            short8 ah0 = *(const short8*)(sH + (0 * 2 + kf) * 512 + l * 8);
            short8 ah1 = *(const short8*)(sH + (1 * 2 + kf) * 512 + l * 8);
            short8 al0 = *(const short8*)(sL + (0 * 2 + kf) * 512 + l * 8);
            short8 al1 = *(const short8*)(sL + (1 * 2 + kf) * 512 + l * 8);
#pragma unroll
            for (int t = 0; t < 3; ++t) {
                int nt = w * 3 + t;
                short8 bh = *(const short8*)(fh + (size_t)(nt * 2 + kf) * 512 + l * 8);
                short8 bl = *(const short8*)(fl + (size_t)(nt * 2 + kf) * 512 + l * 8);
                acc[t][0] = __builtin_amdgcn_mfma_f32_16x16x32_bf16(ah0, bh, acc[t][0], 0, 0, 0);
                acc[t][0] = __builtin_amdgcn_mfma_f32_16x16x32_bf16(al0, bh, acc[t][0], 0, 0, 0);
                acc[t][0] = __builtin_amdgcn_mfma_f32_16x16x32_bf16(ah0, bl, acc[t][0], 0, 0, 0);
                acc[t][1] = __builtin_amdgcn_mfma_f32_16x16x32_bf16(ah1, bh, acc[t][1], 0, 0, 0);
                acc[t][1] = __builtin_amdgcn_mfma_f32_16x16x32_bf16(al1, bh, acc[t][1], 0, 0, 0);
                acc[t][1] = __builtin_amdgcn_mfma_f32_16x16x32_bf16(ah1, bl, acc[t][1], 0, 0, 0);
            }
#pragma unroll
            for (int t = 0; t < 2; ++t) {
                int nt = w * 2 + t;
                short8 bh = *(const short8*)(qh + (size_t)(nt * 2 + kf) * 512 + l * 8);
                short8 bl = *(const short8*)(ql + (size_t)(nt * 2 + kf) * 512 + l * 8);
                accg[t] = __builtin_amdgcn_mfma_f32_16x16x32_bf16(ah0, bh, accg[t], 0, 0, 0);
                accg[t] = __builtin_amdgcn_mfma_f32_16x16x32_bf16(al0, bh, accg[t], 0, 0, 0);
                accg[t] = __builtin_amdgcn_mfma_f32_16x16x32_bf16(ah0, bl, accg[t], 0, 0, 0);
            }
        }
#pragma unroll
        for (int t = 0; t < 3; ++t) {
            int col = (w * 3 + t) * 16 + (l & 15);
            float bias = attn_in_b[col];
#pragma unroll
            for (int r = 0; r < 4; ++r) {
                int row = (l >> 4) * 4 + r;
                qkv[row * 200 + col] = acc[t][0][r] + bias;
            }
            if ((l >> 4) == 0) qkv[16 * 200 + col] = acc[t][1][0] + bias;
        }
#pragma unroll
        for (int t = 0; t < 2; ++t) {
            int col = (w * 2 + t) * 16 + (l & 15);
            if ((l >> 4) == 0) hsh[col] = accg[t][0] + g1_b[col];
        }
    }
    __syncthreads();

    // Phase 3: scores via DPP 16-lane reduce, lane-local softmax, ctx.
    {
        int g = l >> 4;
        float kc[SEQL], vc[SEQL];
#pragma unroll
        for (int j = 0; j < SEQL; ++j) {
            kc[j] = qkv[j * 200 + 64 + g * 16 + (l & 15)];
            vc[j] = qkv[j * 200 + 128 + l];
        }
        for (int i = w * 4 + 1; i <= w * 4 + 4; ++i) {
            float qi = qkv[i * 200 + g * 16 + (l & 15)];
            float sj[SEQL];
#pragma unroll
            for (int j = 0; j < SEQL; ++j) {
                sj[j] = rsum16(qi * kc[j]) * 0.25f;
            }
            float m = sj[0];
#pragma unroll
            for (int j = 1; j < SEQL; ++j) m = fmaxf(m, sj[j]);
            float ssum = 0.f;
#pragma unroll
            for (int j = 0; j < SEQL; ++j) { sj[j] = __expf(sj[j] - m); ssum += sj[j]; }
            float inv = 1.f / ssum;
            float c = 0.f;
#pragma unroll
            for (int j = 0; j < SEQL; ++j) c += sj[j] * vc[j];
            c *= inv;
            unsigned short ch = f2bf(c);
            unsigned short cl = f2bf(c - bf2f(ch));
            int ls = ((i - 1) & 15) + (((l >> 3) & 3) << 4);
            int kf = l >> 5;
            int j2 = l & 7;
            size_t off = (size_t)kf * 512 + ls * 8 + j2;
            ctxH[off] = ch;
            ctxL[off] = cl;
        }
    }
    __syncthreads();

    // Phase 4: attn_out = ctx @ aow^T via MFMA (wave w: N-tile w)
    {
        const unsigned short* gh = (const unsigned short*)(ws + WS_AOWFH);
        const unsigned short* gl = (const unsigned short*)(ws + WS_AOWFL);
        f32x4 acc0 = {0.f, 0.f, 0.f, 0.f};
#pragma unroll
        for (int kf = 0; kf < 2; ++kf) {
            short8 ah = *(const short8*)(ctxH + kf * 512 + l * 8);
            short8 al = *(const short8*)(ctxL + kf * 512 + l * 8);
            short8 bh = *(const short8*)(gh + (size_t)(w * 2 + kf) * 512 + l * 8);
            short8 bl = *(const short8*)(gl + (size_t)(w * 2 + kf) * 512 + l * 8);
            acc0 = __builtin_amdgcn_mfma_f32_16x16x32_bf16(ah, bh, acc0, 0, 0, 0);
            acc0 = __builtin_amdgcn_mfma_f32_16x16x32_bf16(al, bh, acc0, 0, 0, 0);
            acc0 = __builtin_amdgcn_mfma_f32_16x16x32_bf16(ah, bl, acc0, 0, 0, 0);
        }
        __syncthreads();
        {
            int col = w * 16 + (l & 15);
            float bias = attn_out_b[col];
#pragma unroll
            for (int r = 0; r < 4; ++r) {
                int row = (l >> 4) * 4 + r;
                ao[row * 72 + col] = acc0[r] + bias;
            }
        }
    }
    __syncthreads();

    // Phase 5a: gb from g1 preacts (MFMA-produced): gelu + g2 (4 rsum64s)
    float gbv[4];
    {
        float h0 = gelu_exact(hsh[2 * l]);
        float h1 = gelu_exact(hsh[2 * l + 1]);
#pragma unroll
        for (int oo = 0; oo < 4; ++oo) {
            int o = w * 4 + oo;
            gbv[oo] = rsum64(h0 * g2_w[(size_t)o * 128 + 2 * l] +
                             h1 * g2_w[(size_t)o * 128 + 2 * l + 1]) + g2_b[o];
        }
    }

    // Phase 5b: residual + LN + logits (wave w: e = w*4..w*4+3)
    float rs[SEQL];
#pragma unroll
    for (int i = 1; i < SEQL; ++i) rs[i] = seqc[i] + ao[(i - 1) * 72 + l];

    float c1 = ln_w[l] * ls_w[l];
    float c1sum = rsum64(c1);
    float c0sum = rsum64(ln_b[l] * ls_w[l]);
    float lsb0 = ls_b[0];
#pragma unroll
    for (int ee = 0; ee < 4; ++ee) {
        int e = w * 4 + ee;
        float x = rs[e + 1];
        float s1 = rsum64(x);
        float s2 = rsum64(x * x);
        float s3 = rsum64(x * c1);
        float mu = s1 * (1.0f / DLQ);
        float var = s2 * (1.0f / DLQ) - mu * mu;
        float rstd = rsqrtf(var + 1e-5f);
        float lgv = rstd * (s3 - mu * c1sum) + c0sum + lsb0 + gbv[ee];
        if (l == 0) lgv_sh[e] = lgv;
    }
    __syncthreads();

    // softmax + top2 (only wave 0 commits)
    if (w == 0) {
        float p[NE];
        float lgv[NE];
#pragma unroll
        for (int e = 0; e < NE; ++e) lgv[e] = lgv_sh[e];
        float m = lgv[0];
#pragma unroll
        for (int e = 1; e < NE; ++e) m = fmaxf(m, lgv[e]);
        float ssum = 0.f;
#pragma unroll
        for (int e = 0; e < NE; ++e) { p[e] = __expf(lgv[e] - m); ssum += p[e]; }
        float inv = 1.f / ssum;
#pragma unroll
        for (int e = 0; e < NE; ++e) p[e] *= inv;
        int t0 = 0; float b0 = p[0];
#pragma unroll
        for (int e = 1; e < NE; ++e) if (p[e] > b0) { b0 = p[e]; t0 = e; }
        int t1 = -1; float b1 = -1.f;
#pragma unroll
        for (int e = 0; e < NE; ++e) if (e != t0 && p[e] > b1) { b1 = p[e]; t1 = e; }

        float sw = b0 + b1;
        float tw0 = b0 / sw, tw1 = b1 / sw;
        // ACT epilogue: gelu(ef of selected experts) * weight, bf16
        unsigned short* actp = (unsigned short*)(ws + WS_ACT);
        float efv0 = ws[WS_EF + (size_t)n * DMODEL + t0 * DLQ + l] +
                     ws[WS_P1 + (size_t)n * DMODEL + t0 * DLQ + l];
        float efv1 = ws[WS_EF + (size_t)n * DMODEL + t1 * DLQ + l] +
                     ws[WS_P1 + (size_t)n * DMODEL + t1 * DLQ + l];
        actp[(size_t)(n * 2 + 0) * 64 + l] = f2bf(gelu_exact(efv0) * tw0);
        actp[(size_t)(n * 2 + 1) * 64 + l] = f2bf(gelu_exact(efv1) * tw1);
        if (l == 0) {
#pragma unroll
            for (int e = 0; e < NE; ++e) ws[WS_PR + (size_t)n * NE + e] = p[e];
            ((int*)(ws + WS_TI))[n] = t0 | (t1 << 8);
        }
    }
}

// K4 (fused): blocks (e<16, ct): expert-major MoE GEMM. B-frags now TWO
// coalesced 16B loads from the prep-converted w_up plane, issued BEFORE
// compaction so their latency hides under the ballot/LDS work (r10
// theory: the old 16-load 4KB-strided gather + 32 f2bf serialized ahead
// of the MFMA loop). Ballot-compacted token list, MFMA, atomicAdd into
// zeroed out. Block (16, 0): aux loss (plain store).
__global__ __launch_bounds__(256) void k_moe_gemm(float* __restrict__ ws,
                                                  float* __restrict__ out) {
    __shared__ int lst[2048];
    __shared__ int lcnt;
    __shared__ float wsum[4][NE];
    __shared__ int hist[NE];
    int tid = threadIdx.x;
    int wv = tid >> 6, l = tid & 63;

    if (blockIdx.x == NE) {
        if (blockIdx.y != 0) return;
        if (tid < NE) hist[tid] = 0;
        __syncthreads();
        {
            const int* tip = (const int*)(ws + WS_TI);
#pragma unroll
            for (int c = 0; c < 4; ++c) {
                int pk = tip[tid * 4 + c];
                atomicAdd(&hist[pk & 0xff], 1);
                atomicAdd(&hist[(pk >> 8) & 0xff], 1);
            }
        }
        float p[NE];
#pragma unroll
        for (int e = 0; e < NE; ++e) p[e] = 0.f;
        const float* pr = ws + WS_PR + (size_t)tid * 64;
#pragma unroll
        for (int r = 0; r < 4; ++r)
#pragma unroll
            for (int q = 0; q < 4; ++q) {
                float4 v = *(const float4*)(pr + r * 16 + q * 4);
                p[q * 4 + 0] += v.x; p[q * 4 + 1] += v.y;
                p[q * 4 + 2] += v.z; p[q * 4 + 3] += v.w;
            }
#pragma unroll
        for (int e = 0; e < NE; ++e) p[e] = rsum64(p[e]);
        if (l == 0) {
#pragma unroll
            for (int e = 0; e < NE; ++e) wsum[wv][e] = p[e];
        }
        __syncthreads();
        if (tid == 0) {
            float s = 0.f;
#pragma unroll
            for (int e = 0; e < NE; ++e) {
                float sp = wsum[0][e] + wsum[1][e] + wsum[2][e] + wsum[3][e];
                s += sp * (float)hist[e];
            }
            out[(size_t)NTOK * DMODEL] = (float)NE * s / ((float)NTOK * (float)NTOK);
        }
        return;
    }

    // ---- MoE GEMM ----
    int e = blockIdx.x, ct = blockIdx.y;
    // B-frag loads first: independent of compaction; latency hides under it.
    const unsigned short* upf = (const unsigned short*)(ws + WS_UPF) +
                                (size_t)(e * 16 + ct) * 4096 + wv * 1024 + l * 8;
    short8 bf0 = *(const short8*)(upf);
    short8 bf1 = *(const short8*)(upf + 512);

    if (tid == 0) lcnt = 0;
    __syncthreads();
    {
        const int* tip = (const int*)(ws + WS_TI);
#pragma unroll
        for (int c = 0; c < 4; ++c) {
            int tok = wv * 256 + c * 64 + l;
            int pk = tip[tok];
            bool m1 = ((pk >> 8) & 0xff) == e;
            bool m = ((pk & 0xff) == e) || m1;
            unsigned long long mask = __ballot(m);
            int base = 0;
            if (l == 0 && mask) base = atomicAdd(&lcnt, __popcll(mask));
            base = __shfl(base, 0);
            if (m) {
                int pos = base + __popcll(mask & ((1ull << l) - 1ull));
                lst[pos] = tok * 2 + (m1 ? 1 : 0);
            }
        }
    }
    __syncthreads();
    int cnt = lcnt;
    if (cnt == 0) return;

    int col = ct * 64 + wv * 16 + (l & 15);
    int kb = (l >> 4) * 8;
    const unsigned short* actp = (const unsigned short*)(ws + WS_ACT);
    int cr = (l >> 4) * 4;

    for (int mt = 0; mt < cnt; mt += 16) {
        int row = mt + (l & 15);
        short8 a0 = {0, 0, 0, 0, 0, 0, 0, 0};
        short8 a1 = {0, 0, 0, 0, 0, 0, 0, 0};
        if (row < cnt) {
            int pk = lst[row];
            a0 = *(const short8*)(actp + (size_t)pk * 64 + kb);
            a1 = *(const short8*)(actp + (size_t)pk * 64 + 32 + kb);
        }
        f32x4 acc = {0.f, 0.f, 0.f, 0.f};
        acc = __builtin_amdgcn_mfma_f32_16x16x32_bf16(a0, bf0, acc, 0, 0, 0);
        acc = __builtin_amdgcn_mfma_f32_16x16x32_bf16(a1, bf1, acc, 0, 0, 0);
#pragma unroll
        for (int r = 0; r < 4; ++r) {
            int rr = mt + cr + r;
            if (rr < cnt) {
                int pk = lst[rr];
                atomicAdd(&out[(size_t)(pk >> 1) * DMODEL + col], acc[r]);
            }
        }
    }
}

extern "C" void kernel_launch(void* const* d_in, const int* in_sizes, int n_in,
                              void* d_out, int out_size, void* d_ws, size_t ws_size,
                              hipStream_t stream) {
    const float* x          = (const float*)d_in[0];
    const float* w_down     = (const float*)d_in[1];
    const float* pos_embed  = (const float*)d_in[2];
    const float* gp_w       = (const float*)d_in[3];
    const float* gp_b       = (const float*)d_in[4];
    const float* attn_in_w  = (const float*)d_in[5];
    const float* attn_in_b  = (const float*)d_in[6];
    const float* attn_out_w = (const float*)d_in[7];
    const float* attn_out_b = (const float*)d_in[8];
    const float* ln_w       = (const float*)d_in[9];
    const float* ln_b       = (const float*)d_in[10];
    const float* ls_w       = (const float*)d_in[11];
    const float* ls_b       = (const float*)d_in[12];
    const float* g1_w       = (const float*)d_in[13];
    const float* g1_b       = (const float*)d_in[14];
    const float* g2_w       = (const float*)d_in[15];
    const float* g2_b       = (const float*)d_in[16];
    const float* w_up       = (const float*)d_in[17];
    float* ws  = (float*)d_ws;
    float* out = (float*)d_out;

    k_prep<<<1057, 256, 0, stream>>>(x, w_down, attn_in_w, attn_out_w, g1_w,
                                     w_up, ws, out);
    k_ef_mfma<<<516, 256, 0, stream>>>(gp_w, gp_b, ws);
    k_attn2<<<NTOK, 256, 0, stream>>>(pos_embed, attn_in_b, attn_out_b,
                                      ln_w, ln_b, ls_w, ls_b,
                                      g1_b, g2_w, g2_b, ws);
    k_moe_gemm<<<dim3(NE + 1, 16), 256, 0, stream>>>(ws, out);
}

// Round 12
// 159.351 us; speedup vs baseline: 1.0133x; 1.0133x over previous
//
#include <hip/hip_runtime.h>
#include <math.h>

// Problem constants
#define NB 4
#define TT 256
#define DMODEL 1024
#define NE 16
#define DLQ 64
#define NH 4
#define HD 16
#define SEQL 17
#define NTOK 1024   // NB*TT

// Workspace layout (float offsets). ws is ~268 MB; regions are private.
static constexpr size_t WS_EF    = 0;          // 1024x1024 fp32 ef partial P0
static constexpr size_t WS_AH    = 1048576;    // x hi bf16 plane, frag-swizzled
static constexpr size_t WS_AL    = 1572864;    // x lo
static constexpr size_t WS_BH    = 2097152;    // w_down hi
static constexpr size_t WS_BL    = 2621440;    // w_down lo
static constexpr size_t WS_P1    = 3145728;    // K-split partial P1
static constexpr size_t WS_ACT   = 4194304;    // act bf16 [2048][64]
static constexpr size_t WS_AIWFH = 4259840;    // attn_in_w hi frags (12288 sh)
static constexpr size_t WS_AIWFL = 4265984;    // attn_in_w lo frags
static constexpr size_t WS_AOWFH = 4272128;    // attn_out_w hi frags (4096 sh)
static constexpr size_t WS_AOWFL = 4274176;    // attn_out_w lo frags
static constexpr size_t WS_G1FH  = 4276224;    // g1_w hi frags (8192 sh)
static constexpr size_t WS_G1FL  = 4280320;    // g1_w lo frags
static constexpr size_t WS_PR    = 4308992;    // 1024x16 probs
static constexpr size_t WS_TI    = 4325376;    // 1024 packed ints: t0 | t1<<8
static constexpr size_t WS_GCTX  = 4326400;    // 4x64
static constexpr size_t WS_XPART = 4465664;    // [4][8][1024] fp32 x col-sum partials

typedef __attribute__((ext_vector_type(8))) short short8;
typedef __attribute__((ext_vector_type(4))) short short4v;
typedef __attribute__((ext_vector_type(4))) float f32x4;

__device__ __forceinline__ float gelu_exact(float x) {
    return 0.5f * x * (1.0f + erff(x * 0.70710678118654752f));
}

__device__ __forceinline__ unsigned short f2bf(float f) {
    unsigned int u = __float_as_uint(f);
    unsigned int r = (u + 0x7fffu + ((u >> 16) & 1u)) >> 16;
    return (unsigned short)r;
}
__device__ __forceinline__ float bf2f(unsigned short h) {
    return __uint_as_float(((unsigned int)h) << 16);
}

// DPP row_ror all-reduce within 16-lane rows: VALU pipe, zero LDS ops.
#define DPP_ADD(v, ctrl) { int _m = __builtin_amdgcn_update_dpp(0, __float_as_int(v), ctrl, 0xF, 0xF, true); \
                           v += __int_as_float(_m); }
__device__ __forceinline__ float rsum16(float v) {
    DPP_ADD(v, 0x128);  // row_ror:8
    DPP_ADD(v, 0x124);  // row_ror:4
    DPP_ADD(v, 0x122);  // row_ror:2
    DPP_ADD(v, 0x121);  // row_ror:1
    return v;
}
__device__ __forceinline__ float rsum64(float v) {
    v = rsum16(v);
    v += __shfl_xor(v, 16);
    v += __shfl_xor(v, 32);
    return v;
}

// K0 (fused). r11 post-mortem: w_up pre-conversion was neutral-to-negative
// (moe's B-gather was already latency-hidden; prep gained 256 blocks) —
// REVERTED to the r10-proven 159.9us configuration.
// Blocks 0..511: x / w_down hi/lo bf16 frag planes (coalesced read ->
// LDS frag image -> contiguous write). Block 512: weight frag planes.
// Blocks 513..544: x per-batch column-sum partials (no atomics).
// Blocks 545..800: zero out (256 x 4096 floats = NTOK*DMODEL exactly).
__global__ __launch_bounds__(256) void k_prep(const float* __restrict__ x,
                                              const float* __restrict__ wdn,
                                              const float* __restrict__ aiw,
                                              const float* __restrict__ aow,
                                              const float* __restrict__ g1w,
                                              float* __restrict__ ws,
                                              float* __restrict__ out) {
    __shared__ __attribute__((aligned(16))) unsigned short sh_h[4096];
    __shared__ __attribute__((aligned(16))) unsigned short sh_l[4096];
    int bi = blockIdx.x;
    int tid = threadIdx.x;
    if (bi < 512) {
        int which = bi >> 8;            // 0: x, 1: w_down
        int tix = bi & 255;             // tile index = nb*16 + kb
        int nb = tix >> 4, kb = tix & 15;
        const float* src = (which ? wdn : x) + (size_t)(nb * 64) * DMODEL + kb * 64;
        int r = tid >> 2;               // 0..63 (tile row)
        int c4 = (tid & 3) * 4;         // col sub-chunk
#pragma unroll
        for (int q = 0; q < 4; ++q) {
            int cc = q * 16 + c4;       // tile col of first elem
            float4 v = *(const float4*)(src + (size_t)r * DMODEL + cc);
            float a[4] = {v.x, v.y, v.z, v.w};
            unsigned short h4[4], l4[4];
#pragma unroll
            for (int k = 0; k < 4; ++k) {
                h4[k] = f2bf(a[k]);
                l4[k] = f2bf(a[k] - bf2f(h4[k]));
            }
            int st = r >> 4;
            int ks = cc >> 5;
            int ln = (r & 15) + (((cc >> 3) & 3) << 4);
            int jb = cc & 7;            // 0 or 4
            size_t off = (size_t)st * 1024 + ks * 512 + ln * 8 + jb;
            *(short4v*)(sh_h + off) = *(short4v*)h4;
            *(short4v*)(sh_l + off) = *(short4v*)l4;
        }
        __syncthreads();
        unsigned short* hp = (unsigned short*)(ws + (which ? WS_BH : WS_AH)) + (size_t)tix * 4096;
        unsigned short* lp = (unsigned short*)(ws + (which ? WS_BL : WS_AL)) + (size_t)tix * 4096;
        *(short8*)(hp + tid * 16)     = *(short8*)(sh_h + tid * 16);
        *(short8*)(hp + tid * 16 + 8) = *(short8*)(sh_h + tid * 16 + 8);
        *(short8*)(lp + tid * 16)     = *(short8*)(sh_l + tid * 16);
        *(short8*)(lp + tid * 16 + 8) = *(short8*)(sh_l + tid * 16 + 8);
    } else if (bi == 512) {
        unsigned short* fh = (unsigned short*)(ws + WS_AIWFH);
        unsigned short* fl = (unsigned short*)(ws + WS_AIWFL);
        for (int idx = tid; idx < 12 * 2 * 64; idx += 256) {
            int nt = idx >> 7, kf = (idx >> 6) & 1, l = idx & 63;
            int row = nt * 16 + (l & 15);
            int k = kf * 32 + ((l >> 4) << 3);
            const float* src = aiw + (size_t)row * DLQ + k;
            unsigned short h8[8], l8[8];
#pragma unroll
            for (int j = 0; j < 8; ++j) {
                h8[j] = f2bf(src[j]);
                l8[j] = f2bf(src[j] - bf2f(h8[j]));
            }
            size_t off = (size_t)(nt * 2 + kf) * 512 + l * 8;
            *(short8*)(fh + off) = *(short8*)h8;
            *(short8*)(fl + off) = *(short8*)l8;
        }
        unsigned short* gh = (unsigned short*)(ws + WS_AOWFH);
        unsigned short* gl = (unsigned short*)(ws + WS_AOWFL);
        for (int idx = tid; idx < 4 * 2 * 64; idx += 256) {
            int nt = idx >> 7, kf = (idx >> 6) & 1, l = idx & 63;
            int row = nt * 16 + (l & 15);
            int k = kf * 32 + ((l >> 4) << 3);
            const float* src = aow + (size_t)row * DLQ + k;
            unsigned short h8[8], l8[8];
#pragma unroll
            for (int j = 0; j < 8; ++j) {
                h8[j] = f2bf(src[j]);
                l8[j] = f2bf(src[j] - bf2f(h8[j]));
            }
            size_t off = (size_t)(nt * 2 + kf) * 512 + l * 8;
            *(short8*)(gh + off) = *(short8*)h8;
            *(short8*)(gl + off) = *(short8*)l8;
        }
        // g1_w [128][64] -> 8 N-tiles of hi/lo frags (rides attn phase 2)
        unsigned short* qh = (unsigned short*)(ws + WS_G1FH);
        unsigned short* ql = (unsigned short*)(ws + WS_G1FL);
        for (int idx = tid; idx < 8 * 2 * 64; idx += 256) {
            int nt = idx >> 7, kf = (idx >> 6) & 1, l = idx & 63;
            int row = nt * 16 + (l & 15);
            int k = kf * 32 + ((l >> 4) << 3);
            const float* src = g1w + (size_t)row * DLQ + k;
            unsigned short h8[8], l8[8];
#pragma unroll
            for (int j = 0; j < 8; ++j) {
                h8[j] = f2bf(src[j]);
                l8[j] = f2bf(src[j] - bf2f(h8[j]));
            }
            size_t off = (size_t)(nt * 2 + kf) * 512 + l * 8;
            *(short8*)(qh + off) = *(short8*)h8;
            *(short8*)(ql + off) = *(short8*)l8;
        }
    } else if (bi < 545) {
        // x column-sum partials: idx = b*8 + j, rows b*256+j*32 .. +31
        int idx = bi - 513;           // 0..31
        int b = idx >> 3, j = idx & 7;
        const float* xb = x + (size_t)(b * 256 + j * 32) * DMODEL + tid * 4;
        float4 acc = {0.f, 0.f, 0.f, 0.f};
#pragma unroll 8
        for (int r = 0; r < 32; ++r) {
            float4 v = *(const float4*)(xb + (size_t)r * DMODEL);
            acc.x += v.x; acc.y += v.y; acc.z += v.z; acc.w += v.w;
        }
        *(float4*)(ws + WS_XPART + (size_t)idx * DMODEL + tid * 4) = acc;
    } else {
        // zero out[0 .. NTOK*DMODEL): block z covers [z*4096, z*4096+4096)
        int z = bi - 545;             // 0..255
        float4 zz = {0.f, 0.f, 0.f, 0.f};
        float* op = out + (size_t)z * 4096;
#pragma unroll
        for (int q = 0; q < 4; ++q)
            *(float4*)(op + q * 1024 + tid * 4) = zz;
    }
}

// K2: ef GEMM (blocks 0..511, XCD-rectangle swizzle, global_load_lds from
// pre-converted planes) + FOUR gctx tail blocks (bi=512..515, one batch
// each, hidden under the GEMM wall). g1/g2 live in k_attn2 (g1 via MFMA).
__global__ __launch_bounds__(256) void k_ef_mfma(const float* __restrict__ gp_w,
                                                 const float* __restrict__ gp_b,
                                                 float* __restrict__ ws) {
    __shared__ __attribute__((aligned(16))) unsigned short smem[16384];
    int tid = threadIdx.x;
    int bi = blockIdx.x;

    if (bi >= 512) {
        // ---- gctx tail: batch q; wave wv owns cols c = wv*16..+15 ----
        int q = bi - 512;
        int wv = tid >> 6, l = tid & 63;
        float4 xa[4] = {{0.f,0.f,0.f,0.f},{0.f,0.f,0.f,0.f},
                        {0.f,0.f,0.f,0.f},{0.f,0.f,0.f,0.f}};
        const float* xp = ws + WS_XPART + (size_t)q * 8 * DMODEL + l * 16;
#pragma unroll
        for (int j = 0; j < 8; ++j) {
#pragma unroll
            for (int qq = 0; qq < 4; ++qq) {
                float4 v = *(const float4*)(xp + (size_t)j * DMODEL + qq * 4);
                xa[qq].x += v.x; xa[qq].y += v.y; xa[qq].z += v.z; xa[qq].w += v.w;
            }
        }
        float xm[16];
#pragma unroll
        for (int qq = 0; qq < 4; ++qq) {
            xm[qq * 4 + 0] = xa[qq].x * (1.0f / TT);
            xm[qq * 4 + 1] = xa[qq].y * (1.0f / TT);
            xm[qq * 4 + 2] = xa[qq].z * (1.0f / TT);
            xm[qq * 4 + 3] = xa[qq].w * (1.0f / TT);
        }
#pragma unroll 4
        for (int cq = 0; cq < 16; ++cq) {
            int c = wv * 16 + cq;
            const float* gw = gp_w + (size_t)c * DMODEL + l * 16;
            float s = 0.f;
#pragma unroll
            for (int qq = 0; qq < 4; ++qq) {
                float4 w4 = *(const float4*)(gw + qq * 4);
                s += xm[qq * 4 + 0] * w4.x + xm[qq * 4 + 1] * w4.y +
                     xm[qq * 4 + 2] * w4.z + xm[qq * 4 + 3] * w4.w;
            }
            s = rsum64(s);
            if (l == 0) ws[WS_GCTX + q * DLQ + c] = s + gp_b[c];
        }
        return;
    }

    // ---- ef GEMM ----
    int xcd = bi & 7;
    int g   = bi >> 3;
    int kz  = g >> 5;
    int rem = g & 31;
    int nb  = (xcd >> 1) * 4 + (rem >> 3);
    int mb  = (xcd & 1) * 8 + (rem & 7);

    const unsigned short* AhP = (const unsigned short*)(ws + WS_AH);
    const unsigned short* AlP = (const unsigned short*)(ws + WS_AL);
    const unsigned short* BhP = (const unsigned short*)(ws + WS_BH);
    const unsigned short* BlP = (const unsigned short*)(ws + WS_BL);
    int w = tid >> 6, l = tid & 63;
    int wn = (w >> 1) * 32, wm = (w & 1) * 32;
    int stA = wn >> 4, stB = wm >> 4;
    f32x4 acc00 = {0.f, 0.f, 0.f, 0.f}, acc01 = acc00, acc10 = acc00, acc11 = acc00;

    for (int it = 0; it < 8; ++it) {
        int kb = kz * 8 + it;
        const char* srcs[4] = {
            (const char*)(AhP + (size_t)(nb * 16 + kb) * 4096),
            (const char*)(AlP + (size_t)(nb * 16 + kb) * 4096),
            (const char*)(BhP + (size_t)(mb * 16 + kb) * 4096),
            (const char*)(BlP + (size_t)(mb * 16 + kb) * 4096)};
#pragma unroll
        for (int p = 0; p < 4; ++p) {
#pragma unroll
            for (int h = 0; h < 2; ++h) {
                __builtin_amdgcn_global_load_lds(
                    (const __attribute__((address_space(1))) void*)(srcs[p] + h * 4096 + tid * 16),
                    (__attribute__((address_space(3))) void*)((char*)smem + p * 8192 + h * 4096 + tid * 16),
                    16, 0, 0);
            }
        }
        __syncthreads();
        const unsigned short* Ah = smem;
        const unsigned short* Al = smem + 4096;
        const unsigned short* Bh = smem + 8192;
        const unsigned short* Bl = smem + 12288;
#pragma unroll
        for (int ks = 0; ks < 2; ++ks) {
            short8 ah0 = *(const short8*)(Ah + (stA + 0) * 1024 + ks * 512 + l * 8);
            short8 ah1 = *(const short8*)(Ah + (stA + 1) * 1024 + ks * 512 + l * 8);
            short8 al0 = *(const short8*)(Al + (stA + 0) * 1024 + ks * 512 + l * 8);
            short8 al1 = *(const short8*)(Al + (stA + 1) * 1024 + ks * 512 + l * 8);
            short8 bh0 = *(const short8*)(Bh + (stB + 0) * 1024 + ks * 512 + l * 8);
            short8 bh1 = *(const short8*)(Bh + (stB + 1) * 1024 + ks * 512 + l * 8);
            short8 bl0 = *(const short8*)(Bl + (stB + 0) * 1024 + ks * 512 + l * 8);
            short8 bl1 = *(const short8*)(Bl + (stB + 1) * 1024 + ks * 512 + l * 8);
            acc00 = __builtin_amdgcn_mfma_f32_16x16x32_bf16(ah0, bh0, acc00, 0, 0, 0);
            acc00 = __builtin_amdgcn_mfma_f32_16x16x32_bf16(al0, bh0, acc00, 0, 0, 0);
            acc00 = __builtin_amdgcn_mfma_f32_16x16x32_bf16(ah0, bl0, acc00, 0, 0, 0);
            acc01 = __builtin_amdgcn_mfma_f32_16x16x32_bf16(ah0, bh1, acc01, 0, 0, 0);
            acc01 = __builtin_amdgcn_mfma_f32_16x16x32_bf16(al0, bh1, acc01, 0, 0, 0);
            acc01 = __builtin_amdgcn_mfma_f32_16x16x32_bf16(ah0, bl1, acc01, 0, 0, 0);
            acc10 = __builtin_amdgcn_mfma_f32_16x16x32_bf16(ah1, bh0, acc10, 0, 0, 0);
            acc10 = __builtin_amdgcn_mfma_f32_16x16x32_bf16(al1, bh0, acc10, 0, 0, 0);
            acc10 = __builtin_amdgcn_mfma_f32_16x16x32_bf16(ah1, bl0, acc10, 0, 0, 0);
            acc11 = __builtin_amdgcn_mfma_f32_16x16x32_bf16(ah1, bh1, acc11, 0, 0, 0);
            acc11 = __builtin_amdgcn_mfma_f32_16x16x32_bf16(al1, bh1, acc11, 0, 0, 0);
            acc11 = __builtin_amdgcn_mfma_f32_16x16x32_bf16(ah1, bl1, acc11, 0, 0, 0);
        }
        __syncthreads();
    }
    int cr = (l >> 4) * 4, cc = l & 15;
    int n0 = nb * 64;
    float* P = ws + (kz == 0 ? WS_EF : WS_P1);
    int m0 = mb * 64;
#pragma unroll
    for (int r = 0; r < 4; ++r) {
        P[(size_t)(n0 + wn + cr + r) * DMODEL + (m0 + wm + cc)]           = acc00[r];
        P[(size_t)(n0 + wn + cr + r) * DMODEL + (m0 + wm + 16 + cc)]      = acc01[r];
        P[(size_t)(n0 + wn + 16 + cr + r) * DMODEL + (m0 + wm + cc)]      = acc10[r];
        P[(size_t)(n0 + wn + 16 + cr + r) * DMODEL + (m0 + wm + 16 + cc)] = acc11[r];
    }
}

// K3: one token per block, FOUR waves. MFMA qkv/attn_out + g1-preacts,
// DPP reduces, ACT epilogue. (r6/r8/r10-proven, byte-identical.)
__global__ __launch_bounds__(256) void k_attn2(const float* __restrict__ pos_embed,
                                               const float* __restrict__ attn_in_b,
                                               const float* __restrict__ attn_out_b,
                                               const float* __restrict__ ln_w,
                                               const float* __restrict__ ln_b,
                                               const float* __restrict__ ls_w,
                                               const float* __restrict__ ls_b,
                                               const float* __restrict__ g1_b,
                                               const float* __restrict__ g2_w,
                                               const float* __restrict__ g2_b,
                                               float* __restrict__ ws) {
    int n = blockIdx.x;
    int w = threadIdx.x >> 6;    // 0..3
    int l = threadIdx.x & 63;
    int b = n >> 8;

    __shared__ float qkv[SEQL * 200];
    __shared__ __attribute__((aligned(16))) char ubuf[8192];   // sH/sL then ao
    __shared__ __attribute__((aligned(16))) unsigned short ctxH[1024];
    __shared__ __attribute__((aligned(16))) unsigned short ctxL[1024];
    __shared__ float lgv_sh[NE];
    __shared__ float hsh[128];   // g1 preacts (bias added, gelu at read)
    unsigned short* sH = (unsigned short*)ubuf;
    unsigned short* sL = (unsigned short*)(ubuf + 4096);
    float* ao = (float*)ubuf;

    // Phase 1: seq = (P0+P1)[n] + pos (row 0 = gctx); column l in regs.
    float seqc[SEQL];
    float gcv = ws[WS_GCTX + b * DLQ + l];
    {
        const float* efp0 = ws + WS_EF + (size_t)n * DMODEL;
        const float* efp1 = ws + WS_P1 + (size_t)n * DMODEL;
#pragma unroll
        for (int i = 0; i < SEQL; ++i) {
            float s = (i == 0) ? gcv
                               : efp0[(i - 1) * DLQ + l] + efp1[(i - 1) * DLQ + l] +
                                 pos_embed[(i - 1) * DLQ + l];
            seqc[i] = s;
            int lo_r = w * 5, hi_r = w * 5 + 4;
            if (i >= lo_r && i <= hi_r) {
                unsigned short hs = f2bf(s);
                unsigned short lsv = f2bf(s - bf2f(hs));
                int mt = i >> 4;
                int ls = (i & 15) + (((l >> 3) & 3) << 4);
                int kf = l >> 5;
                int j = l & 7;
                size_t off = (size_t)(mt * 2 + kf) * 512 + ls * 8 + j;
                sH[off] = hs;
                sL[off] = lsv;
            }
        }
    }
    __syncthreads();

    // Phase 2: qkv = seq @ aiw^T (wave w: tiles w*3..+2) AND g1 preacts
    {
        const unsigned short* fh = (const unsigned short*)(ws + WS_AIWFH);
        const unsigned short* fl = (const unsigned short*)(ws + WS_AIWFL);
        const unsigned short* qh = (const unsigned short*)(ws + WS_G1FH);
        const unsigned short* ql = (const unsigned short*)(ws + WS_G1FL);
        f32x4 acc[3][2];
        f32x4 accg[2];
#pragma unroll
        for (int t = 0; t < 3; ++t)
#pragma unroll
            for (int m = 0; m < 2; ++m) acc[t][m] = (f32x4){0.f, 0.f, 0.f, 0.f};
#pragma unroll
        for (int t = 0; t < 2; ++t) accg[t] = (f32x4){0.f, 0.f, 0.f, 0.f};
#pragma unroll
        for (int kf = 0; kf < 2; ++kf) {
            short8 ah0 = *(const short8*)(sH + (0 * 2 + kf) * 512 + l * 8);
            short8 ah1 = *(const short8*)(sH + (1 * 2 + kf) * 512 + l * 8);
            short8 al0 = *(const short8*)(sL + (0 * 2 + kf) * 512 + l * 8);
            short8 al1 = *(const short8*)(sL + (1 * 2 + kf) * 512 + l * 8);
#pragma unroll
            for (int t = 0; t < 3; ++t) {
                int nt = w * 3 + t;
                short8 bh = *(const short8*)(fh + (size_t)(nt * 2 + kf) * 512 + l * 8);
                short8 bl = *(const short8*)(fl + (size_t)(nt * 2 + kf) * 512 + l * 8);
                acc[t][0] = __builtin_amdgcn_mfma_f32_16x16x32_bf16(ah0, bh, acc[t][0], 0, 0, 0);
                acc[t][0] = __builtin_amdgcn_mfma_f32_16x16x32_bf16(al0, bh, acc[t][0], 0, 0, 0);
                acc[t][0] = __builtin_amdgcn_mfma_f32_16x16x32_bf16(ah0, bl, acc[t][0], 0, 0, 0);
                acc[t][1] = __builtin_amdgcn_mfma_f32_16x16x32_bf16(ah1, bh, acc[t][1], 0, 0, 0);
                acc[t][1] = __builtin_amdgcn_mfma_f32_16x16x32_bf16(al1, bh, acc[t][1], 0, 0, 0);
                acc[t][1] = __builtin_amdgcn_mfma_f32_16x16x32_bf16(ah1, bl, acc[t][1], 0, 0, 0);
            }
#pragma unroll
            for (int t = 0; t < 2; ++t) {
                int nt = w * 2 + t;
                short8 bh = *(const short8*)(qh + (size_t)(nt * 2 + kf) * 512 + l * 8);
                short8 bl = *(const short8*)(ql + (size_t)(nt * 2 + kf) * 512 + l * 8);
                accg[t] = __builtin_amdgcn_mfma_f32_16x16x32_bf16(ah0, bh, accg[t], 0, 0, 0);
                accg[t] = __builtin_amdgcn_mfma_f32_16x16x32_bf16(al0, bh, accg[t], 0, 0, 0);
                accg[t] = __builtin_amdgcn_mfma_f32_16x16x32_bf16(ah0, bl, accg[t], 0, 0, 0);
            }
        }
#pragma unroll
        for (int t = 0; t < 3; ++t) {
            int col = (w * 3 + t) * 16 + (l & 15);
            float bias = attn_in_b[col];
#pragma unroll
            for (int r = 0; r < 4; ++r) {
                int row = (l >> 4) * 4 + r;
                qkv[row * 200 + col] = acc[t][0][r] + bias;
            }
            if ((l >> 4) == 0) qkv[16 * 200 + col] = acc[t][1][0] + bias;
        }
#pragma unroll
        for (int t = 0; t < 2; ++t) {
            int col = (w * 2 + t) * 16 + (l & 15);
            if ((l >> 4) == 0) hsh[col] = accg[t][0] + g1_b[col];
        }
    }
    __syncthreads();

    // Phase 3: scores via DPP 16-lane reduce, lane-local softmax, ctx.
    {
        int g = l >> 4;
        float kc[SEQL], vc[SEQL];
#pragma unroll
        for (int j = 0; j < SEQL; ++j) {
            kc[j] = qkv[j * 200 + 64 + g * 16 + (l & 15)];
            vc[j] = qkv[j * 200 + 128 + l];
        }
        for (int i = w * 4 + 1; i <= w * 4 + 4; ++i) {
            float qi = qkv[i * 200 + g * 16 + (l & 15)];
            float sj[SEQL];
#pragma unroll
            for (int j = 0; j < SEQL; ++j) {
                sj[j] = rsum16(qi * kc[j]) * 0.25f;
            }
            float m = sj[0];
#pragma unroll
            for (int j = 1; j < SEQL; ++j) m = fmaxf(m, sj[j]);
            float ssum = 0.f;
#pragma unroll
            for (int j = 0; j < SEQL; ++j) { sj[j] = __expf(sj[j] - m); ssum += sj[j]; }
            float inv = 1.f / ssum;
            float c = 0.f;
#pragma unroll
            for (int j = 0; j < SEQL; ++j) c += sj[j] * vc[j];
            c *= inv;
            unsigned short ch = f2bf(c);
            unsigned short cl = f2bf(c - bf2f(ch));
            int ls = ((i - 1) & 15) + (((l >> 3) & 3) << 4);
            int kf = l >> 5;
            int j2 = l & 7;
            size_t off = (size_t)kf * 512 + ls * 8 + j2;
            ctxH[off] = ch;
            ctxL[off] = cl;
        }
    }
    __syncthreads();

    // Phase 4: attn_out = ctx @ aow^T via MFMA (wave w: N-tile w)
    {
        const unsigned short* gh = (const unsigned short*)(ws + WS_AOWFH);
        const unsigned short* gl = (const unsigned short*)(ws + WS_AOWFL);
        f32x4 acc0 = {0.f, 0.f, 0.f, 0.f};
#pragma unroll
        for (int kf = 0; kf < 2; ++kf) {
            short8 ah = *(const short8*)(ctxH + kf * 512 + l * 8);
            short8 al = *(const short8*)(ctxL + kf * 512 + l * 8);
            short8 bh = *(const short8*)(gh + (size_t)(w * 2 + kf) * 512 + l * 8);
            short8 bl = *(const short8*)(gl + (size_t)(w * 2 + kf) * 512 + l * 8);
            acc0 = __builtin_amdgcn_mfma_f32_16x16x32_bf16(ah, bh, acc0, 0, 0, 0);
            acc0 = __builtin_amdgcn_mfma_f32_16x16x32_bf16(al, bh, acc0, 0, 0, 0);
            acc0 = __builtin_amdgcn_mfma_f32_16x16x32_bf16(ah, bl, acc0, 0, 0, 0);
        }
        __syncthreads();
        {
            int col = w * 16 + (l & 15);
            float bias = attn_out_b[col];
#pragma unroll
            for (int r = 0; r < 4; ++r) {
                int row = (l >> 4) * 4 + r;
                ao[row * 72 + col] = acc0[r] + bias;
            }
        }
    }
    __syncthreads();

    // Phase 5a: gb from g1 preacts (MFMA-produced): gelu + g2 (4 rsum64s)
    float gbv[4];
    {
        float h0 = gelu_exact(hsh[2 * l]);
        float h1 = gelu_exact(hsh[2 * l + 1]);
#pragma unroll
        for (int oo = 0; oo < 4; ++oo) {
            int o = w * 4 + oo;
            gbv[oo] = rsum64(h0 * g2_w[(size_t)o * 128 + 2 * l] +
                             h1 * g2_w[(size_t)o * 128 + 2 * l + 1]) + g2_b[o];
        }
    }

    // Phase 5b: residual + LN + logits (wave w: e = w*4..w*4+3)
    float rs[SEQL];
#pragma unroll
    for (int i = 1; i < SEQL; ++i) rs[i] = seqc[i] + ao[(i - 1) * 72 + l];

    float c1 = ln_w[l] * ls_w[l];
    float c1sum = rsum64(c1);
    float c0sum = rsum64(ln_b[l] * ls_w[l]);
    float lsb0 = ls_b[0];
#pragma unroll
    for (int ee = 0; ee < 4; ++ee) {
        int e = w * 4 + ee;
        float x = rs[e + 1];
        float s1 = rsum64(x);
        float s2 = rsum64(x * x);
        float s3 = rsum64(x * c1);
        float mu = s1 * (1.0f / DLQ);
        float var = s2 * (1.0f / DLQ) - mu * mu;
        float rstd = rsqrtf(var + 1e-5f);
        float lgv = rstd * (s3 - mu * c1sum) + c0sum + lsb0 + gbv[ee];
        if (l == 0) lgv_sh[e] = lgv;
    }
    __syncthreads();

    // softmax + top2 (only wave 0 commits)
    if (w == 0) {
        float p[NE];
        float lgv[NE];
#pragma unroll
        for (int e = 0; e < NE; ++e) lgv[e] = lgv_sh[e];
        float m = lgv[0];
#pragma unroll
        for (int e = 1; e < NE; ++e) m = fmaxf(m, lgv[e]);
        float ssum = 0.f;
#pragma unroll
        for (int e = 0; e < NE; ++e) { p[e] = __expf(lgv[e] - m); ssum += p[e]; }
        float inv = 1.f / ssum;
#pragma unroll
        for (int e = 0; e < NE; ++e) p[e] *= inv;
        int t0 = 0; float b0 = p[0];
#pragma unroll
        for (int e = 1; e < NE; ++e) if (p[e] > b0) { b0 = p[e]; t0 = e; }
        int t1 = -1; float b1 = -1.f;
#pragma unroll
        for (int e = 0; e < NE; ++e) if (e != t0 && p[e] > b1) { b1 = p[e]; t1 = e; }

        float sw = b0 + b1;
        float tw0 = b0 / sw, tw1 = b1 / sw;
        // ACT epilogue: gelu(ef of selected experts) * weight, bf16
        unsigned short* actp = (unsigned short*)(ws + WS_ACT);
        float efv0 = ws[WS_EF + (size_t)n * DMODEL + t0 * DLQ + l] +
                     ws[WS_P1 + (size_t)n * DMODEL + t0 * DLQ + l];
        float efv1 = ws[WS_EF + (size_t)n * DMODEL + t1 * DLQ + l] +
                     ws[WS_P1 + (size_t)n * DMODEL + t1 * DLQ + l];
        actp[(size_t)(n * 2 + 0) * 64 + l] = f2bf(gelu_exact(efv0) * tw0);
        actp[(size_t)(n * 2 + 1) * 64 + l] = f2bf(gelu_exact(efv1) * tw1);
        if (l == 0) {
#pragma unroll
            for (int e = 0; e < NE; ++e) ws[WS_PR + (size_t)n * NE + e] = p[e];
            ((int*)(ws + WS_TI))[n] = t0 | (t1 << 8);
        }
    }
}

// K4 (fused): blocks (e<16, ct): expert-major MoE GEMM. B-frags converted
// inline from fp32 w_up (r11: pre-converted planes were neutral-to-negative
// — the gather is latency-hidden; reverted). Ballot-compacted token list,
// MFMA, atomicAdd into zeroed out. Block (16, 0): aux loss (plain store).
__global__ __launch_bounds__(256) void k_moe_gemm(const float* __restrict__ w_up,
                                                  float* __restrict__ ws,
                                                  float* __restrict__ out) {
    __shared__ int lst[2048];
    __shared__ int lcnt;
    __shared__ float wsum[4][NE];
    __shared__ int hist[NE];
    int tid = threadIdx.x;
    int wv = tid >> 6, l = tid & 63;

    if (blockIdx.x == NE) {
        if (blockIdx.y != 0) return;
        if (tid < NE) hist[tid] = 0;
        __syncthreads();
        {
            const int* tip = (const int*)(ws + WS_TI);
#pragma unroll
            for (int c = 0; c < 4; ++c) {
                int pk = tip[tid * 4 + c];
                atomicAdd(&hist[pk & 0xff], 1);
                atomicAdd(&hist[(pk >> 8) & 0xff], 1);
            }
        }
        float p[NE];
#pragma unroll
        for (int e = 0; e < NE; ++e) p[e] = 0.f;
        const float* pr = ws + WS_PR + (size_t)tid * 64;
#pragma unroll
        for (int r = 0; r < 4; ++r)
#pragma unroll
            for (int q = 0; q < 4; ++q) {
                float4 v = *(const float4*)(pr + r * 16 + q * 4);
                p[q * 4 + 0] += v.x; p[q * 4 + 1] += v.y;
                p[q * 4 + 2] += v.z; p[q * 4 + 3] += v.w;
            }
#pragma unroll
        for (int e = 0; e < NE; ++e) p[e] = rsum64(p[e]);
        if (l == 0) {
#pragma unroll
            for (int e = 0; e < NE; ++e) wsum[wv][e] = p[e];
        }
        __syncthreads();
        if (tid == 0) {
            float s = 0.f;
#pragma unroll
            for (int e = 0; e < NE; ++e) {
                float sp = wsum[0][e] + wsum[1][e] + wsum[2][e] + wsum[3][e];
                s += sp * (float)hist[e];
            }
            out[(size_t)NTOK * DMODEL] = (float)NE * s / ((float)NTOK * (float)NTOK);
        }
        return;
    }

    // ---- MoE GEMM ----
    int e = blockIdx.x, ct = blockIdx.y;
    if (tid == 0) lcnt = 0;
    __syncthreads();
    {
        const int* tip = (const int*)(ws + WS_TI);
#pragma unroll
        for (int c = 0; c < 4; ++c) {
            int tok = wv * 256 + c * 64 + l;
            int pk = tip[tok];
            bool m1 = ((pk >> 8) & 0xff) == e;
            bool m = ((pk & 0xff) == e) || m1;
            unsigned long long mask = __ballot(m);
            int base = 0;
            if (l == 0 && mask) base = atomicAdd(&lcnt, __popcll(mask));
            base = __shfl(base, 0);
            if (m) {
                int pos = base + __popcll(mask & ((1ull << l) - 1ull));
                lst[pos] = tok * 2 + (m1 ? 1 : 0);
            }
        }
    }
    __syncthreads();
    int cnt = lcnt;
    if (cnt == 0) return;

    // Inline B-frag conversion: lane needs w_up[e][kb+j][col], j=0..7 (+32)
    int col = ct * 64 + wv * 16 + (l & 15);
    int kb = (l >> 4) * 8;
    const float* wue = w_up + (size_t)e * DLQ * DMODEL + col;
    unsigned short b0v[8], b1v[8];
#pragma unroll
    for (int j = 0; j < 8; ++j) {
        b0v[j] = f2bf(wue[(size_t)(kb + j) * DMODEL]);
        b1v[j] = f2bf(wue[(size_t)(kb + 32 + j) * DMODEL]);
    }
    short8 bf0 = *(short8*)b0v;
    short8 bf1 = *(short8*)b1v;

    const unsigned short* actp = (const unsigned short*)(ws + WS_ACT);
    int cr = (l >> 4) * 4;

    for (int mt = 0; mt < cnt; mt += 16) {
        int row = mt + (l & 15);
        short8 a0 = {0, 0, 0, 0, 0, 0, 0, 0};
        short8 a1 = {0, 0, 0, 0, 0, 0, 0, 0};
        if (row < cnt) {
            int pk = lst[row];
            a0 = *(const short8*)(actp + (size_t)pk * 64 + kb);
            a1 = *(const short8*)(actp + (size_t)pk * 64 + 32 + kb);
        }
        f32x4 acc = {0.f, 0.f, 0.f, 0.f};
        acc = __builtin_amdgcn_mfma_f32_16x16x32_bf16(a0, bf0, acc, 0, 0, 0);
        acc = __builtin_amdgcn_mfma_f32_16x16x32_bf16(a1, bf1, acc, 0, 0, 0);
#pragma unroll
        for (int r = 0; r < 4; ++r) {
            int rr = mt + cr + r;
            if (rr < cnt) {
                int pk = lst[rr];
                atomicAdd(&out[(size_t)(pk >> 1) * DMODEL + col], acc[r]);
            }
        }
    }
}

extern "C" void kernel_launch(void* const* d_in, const int* in_sizes, int n_in,
                              void* d_out, int out_size, void* d_ws, size_t ws_size,
                              hipStream_t stream) {
    const float* x          = (const float*)d_in[0];
    const float* w_down     = (const float*)d_in[1];
    const float* pos_embed  = (const float*)d_in[2];
    const float* gp_w       = (const float*)d_in[3];
    const float* gp_b       = (const float*)d_in[4];
    const float* attn_in_w  = (const float*)d_in[5];
    const float* attn_in_b  = (const float*)d_in[6];
    const float* attn_out_w = (const float*)d_in[7];
    const float* attn_out_b = (const float*)d_in[8];
    const float* ln_w       = (const float*)d_in[9];
    const float* ln_b       = (const float*)d_in[10];
    const float* ls_w       = (const float*)d_in[11];
    const float* ls_b       = (const float*)d_in[12];
    const float* g1_w       = (const float*)d_in[13];
    const float* g1_b       = (const float*)d_in[14];
    const float* g2_w       = (const float*)d_in[15];
    const float* g2_b       = (const float*)d_in[16];
    const float* w_up       = (const float*)d_in[17];
    float* ws  = (float*)d_ws;
    float* out = (float*)d_out;

    k_prep<<<801, 256, 0, stream>>>(x, w_down, attn_in_w, attn_out_w, g1_w, ws, out);
    k_ef_mfma<<<516, 256, 0, stream>>>(gp_w, gp_b, ws);
    k_attn2<<<NTOK, 256, 0, stream>>>(pos_embed, attn_in_b, attn_out_b,
                                      ln_w, ln_b, ls_w, ls_b,
                                      g1_b, g2_w, g2_b, ws);
    k_moe_gemm<<<dim3(NE + 1, 16), 256, 0, stream>>>(w_up, ws, out);
}